// Round 2
// baseline (161.706 us; speedup 1.0000x reference)
//
#include <hip/hip_runtime.h>
#include <math.h>

// InterpolatorMask: out = sum(roll(mask, ind) * yOrig), ind = floor((x-x0)/dx),
// zeroed when x outside [x0, xMax). Equivalently:
//   out = sum_j mask[j] * yOrig[(j + ind) mod N]
//
// Memory-bound on the mask stream (64 MiB). Exact-zero skip: mask[j]==0
// contributes exactly 0 (y finite), so yOrig is gathered only where mask!=0
// (~2 waves for this problem's mask). Floor: 64 MiB / 6.3 TB/s ~= 10.6 us.
//
// R2 changes (overhead trim, same algorithm):
//  - 32 B/thread (2x float4): 131072 waves instead of 262144.
//  - scalar broadcast loads + fdiv/floor moved inside the nonzero branch
//    (only executed by waves that actually see nonzero mask).
//  - butterfly + atomic skipped unless __any(acc != 0) (wave-uniform).

__global__ __launch_bounds__(256) void interp_mask_reduce(
    const float* __restrict__ xp,
    const float* __restrict__ xOrig,
    const float* __restrict__ yOrig,
    const float* __restrict__ mask,
    float* __restrict__ out,
    int n)
{
    float acc = 0.0f;
    const int tid  = blockIdx.x * blockDim.x + threadIdx.x;
    const int base = tid * 8;

    if (base + 8 <= n) {
        const float4 m0 = *reinterpret_cast<const float4*>(mask + base);
        const float4 m1 = *reinterpret_cast<const float4*>(mask + base + 4);
        const bool nz = (m0.x != 0.0f) | (m0.y != 0.0f) | (m0.z != 0.0f) | (m0.w != 0.0f)
                      | (m1.x != 0.0f) | (m1.y != 0.0f) | (m1.z != 0.0f) | (m1.w != 0.0f);
        if (nz) {
            // Cold path: only waves owning nonzero mask pay for these.
            const float xv   = xp[0];
            const float x0   = xOrig[0];
            const float dxv  = xOrig[1] - xOrig[0];
            const float xMax = xOrig[n - 1];
            const float scale = (xv >= x0 && xv < xMax) ? 1.0f : 0.0f;
            long long ind = (long long)floorf((xv - x0) / dxv);
            long long j0  = ((long long)base + ind) % (long long)n;
            if (j0 < 0) j0 += n;
            int jj = (int)j0;
            const float mv[8] = {m0.x, m0.y, m0.z, m0.w, m1.x, m1.y, m1.z, m1.w};
            #pragma unroll
            for (int k = 0; k < 8; ++k) {
                acc += mv[k] * yOrig[jj];
                ++jj; if (jj >= n) jj = 0;  // circular wrap
            }
            acc *= scale;  // exact: invalid x -> acc = 0 -> no atomic
        }
    } else if (base < n) {
        // Generic tail (not reached for n = 2^24; kept for correctness on any n).
        const float xv   = xp[0];
        const float x0   = xOrig[0];
        const float dxv  = xOrig[1] - xOrig[0];
        const float xMax = xOrig[n - 1];
        const float scale = (xv >= x0 && xv < xMax) ? 1.0f : 0.0f;
        long long ind = (long long)floorf((xv - x0) / dxv);
        for (int t = base; t < n; ++t) {
            const float mv = mask[t];
            if (mv != 0.0f) {
                long long j = ((long long)t + ind) % (long long)n;
                if (j < 0) j += n;
                acc += mv * yOrig[(int)j];
            }
        }
        acc *= scale;
    }

    // Wave-uniform skip: ~all waves have acc == 0 exactly and fall through.
    if (__any(acc != 0.0f)) {
        #pragma unroll
        for (int off = 32; off > 0; off >>= 1)
            acc += __shfl_down(acc, off, 64);
        // ~1 atomic total across the grid; adding exact zeros in any order is
        // exact, so fp32 atomic ordering nondeterminism is benign.
        if ((threadIdx.x & 63) == 0 && acc != 0.0f)
            atomicAdd(out, acc);
    }
}

extern "C" void kernel_launch(void* const* d_in, const int* in_sizes, int n_in,
                              void* d_out, int out_size, void* d_ws, size_t ws_size,
                              hipStream_t stream) {
    const float* x     = (const float*)d_in[0];
    const float* xOrig = (const float*)d_in[1];
    const float* yOrig = (const float*)d_in[2];
    const float* mask  = (const float*)d_in[3];
    float* out = (float*)d_out;
    const int n = in_sizes[1];  // length of xOrig / yOrig / mask

    // d_out is poisoned to 0xAA before every timed launch — zero it on-stream.
    hipMemsetAsync(d_out, 0, sizeof(float), stream);

    const int threads = 256;
    const int perBlock = threads * 8;                      // 2048 elements/block
    const int blocks = (n + perBlock - 1) / perBlock;      // 8192 for 2^24
    interp_mask_reduce<<<blocks, threads, 0, stream>>>(x, xOrig, yOrig, mask, out, n);
}